// Round 15
// baseline (296.448 us; speedup 1.0000x reference)
//
#include <hip/hip_runtime.h>
#include <hip/hip_fp16.h>

#define NV 50000
#define EV 800000
#define INF 128
#define HD 64
#define KNEG 5
#define NB ((NV + 1023) / 1024)   // 49 scan blocks

#if defined(__has_builtin)
#if __has_builtin(__builtin_amdgcn_fdot2)
#define HAS_FDOT2 1
#endif
#endif

typedef _Float16 half2r __attribute__((ext_vector_type(2)));

// dot2: c += a.lo*b.lo + a.hi*b.hi  (f16 pairs, f32 accumulate)
__device__ __forceinline__ float dot2acc(unsigned a, unsigned b, float c) {
#ifdef HAS_FDOT2
  return __builtin_amdgcn_fdot2(__builtin_bit_cast(half2r, a),
                                __builtin_bit_cast(half2r, b), c, false);
#else
  const __half2 ha = *(const __half2*)&a;
  const __half2 hb = *(const __half2*)&b;
  return c + __low2float(ha) * __low2float(hb)
           + __high2float(ha) * __high2float(hb);
#endif
}

__device__ __forceinline__ unsigned packh2(float lo, float hi) {
  return __builtin_bit_cast(unsigned, __floats2half2_rn(lo, hi));
}

// ------- embed + hist fused, v6b (unchanged from r13) -----------------
__global__ __launch_bounds__(256) void embed_hist_kernel(
    const float* __restrict__ feat, const float* __restrict__ W,
    const float* __restrict__ b, __half* __restrict__ h,
    const int* __restrict__ dst, int* __restrict__ deg,
    unsigned short* __restrict__ rank) {
  __shared__ unsigned sF[4][2][256];   // wave x buf x 512 halves = 8 KB
  const int lane = threadIdx.x & 63;
  const int wave = threadIdx.x >> 6;
  // zero row NV of h (gather's out-of-degree target) — folded memset
  if (blockIdx.x == 0 && threadIdx.x < 32)
    ((unsigned*)(h + (size_t)NV * HD))[threadIdx.x] = 0u;
  unsigned Wh[64];
#pragma unroll
  for (int j = 0; j < 64; j++)
    Wh[j] = packh2(W[(2 * j) * HD + lane], W[(2 * j + 1) * HD + lane]);
  const float bias = b[lane];
  const int nwaves = gridDim.x * 4;
  const int wid = blockIdx.x * 4 + wave;   // wave-uniform
  const int ngroups = NV / 4;              // 12500 exactly

  int buf = 0;
  int g = wid;
  if (g < ngroups) {
    const float4* gp = (const float4*)(feat + (size_t)g * 512);
    const float4 a0 = gp[lane];
    const float4 a1 = gp[lane + 64];
    uint2 c0, c1;
    c0.x = packh2(a0.x, a0.y); c0.y = packh2(a0.z, a0.w);
    c1.x = packh2(a1.x, a1.y); c1.y = packh2(a1.z, a1.w);
    ((uint2*)sF[wave][0])[lane] = c0;
    ((uint2*)sF[wave][0])[lane + 64] = c1;
  }
  for (; g < ngroups; g += nwaves) {
    const int gn = g + nwaves;
    float4 b0, b1;
    if (gn < ngroups) {                    // wave-uniform guard
      const float4* gp = (const float4*)(feat + (size_t)gn * 512);
      b0 = gp[lane];                       // prefetch next group
      b1 = gp[lane + 64];
    }
    float acc0 = bias, acc1 = bias, acc2 = bias, acc3 = bias;
    const uint4* F = (const uint4*)sF[wave][buf];
#pragma unroll
    for (int t = 0; t < 16; t++) {         // k8 blocks
      const uint4 x0 = F[t];               // broadcast reads (uniform)
      const uint4 x1 = F[16 + t];
      const uint4 x2 = F[32 + t];
      const uint4 x3 = F[48 + t];
      const unsigned w0 = Wh[4 * t + 0];
      const unsigned w1 = Wh[4 * t + 1];
      const unsigned w2 = Wh[4 * t + 2];
      const unsigned w3 = Wh[4 * t + 3];
      acc0 = dot2acc(x0.x, w0, acc0); acc0 = dot2acc(x0.y, w1, acc0);
      acc0 = dot2acc(x0.z, w2, acc0); acc0 = dot2acc(x0.w, w3, acc0);
      acc1 = dot2acc(x1.x, w0, acc1); acc1 = dot2acc(x1.y, w1, acc1);
      acc1 = dot2acc(x1.z, w2, acc1); acc1 = dot2acc(x1.w, w3, acc1);
      acc2 = dot2acc(x2.x, w0, acc2); acc2 = dot2acc(x2.y, w1, acc2);
      acc2 = dot2acc(x2.z, w2, acc2); acc2 = dot2acc(x2.w, w3, acc2);
      acc3 = dot2acc(x3.x, w0, acc3); acc3 = dot2acc(x3.y, w1, acc3);
      acc3 = dot2acc(x3.z, w2, acc3); acc3 = dot2acc(x3.w, w3, acc3);
    }
    __half* hpo = h + (size_t)g * 256 + lane;   // 4 coalesced 128B stores
    hpo[0]   = __float2half_rn(acc0);
    hpo[64]  = __float2half_rn(acc1);
    hpo[128] = __float2half_rn(acc2);
    hpo[192] = __float2half_rn(acc3);
    if (gn < ngroups) {
      uint2 c0, c1;
      c0.x = packh2(b0.x, b0.y); c0.y = packh2(b0.z, b0.w);
      c1.x = packh2(b1.x, b1.y); c1.y = packh2(b1.z, b1.w);
      ((uint2*)sF[wave][buf ^ 1])[lane] = c0;
      ((uint2*)sF[wave][buf ^ 1])[lane + 64] = c1;
      buf ^= 1;
    }
  }
  // hist tail: overlaps with GEMM-bound waves of other blocks
  for (int e = blockIdx.x * 256 + threadIdx.x; e < EV; e += gridDim.x * 256) {
    const int r = atomicAdd(&deg[dst[e]], 1);
    rank[e] = (unsigned short)r;             // coalesced u16 store
  }
}

// ------- parallel scan, pass 1 ----------------------------------------
__global__ __launch_bounds__(1024) void scan_part_kernel(
    const int* __restrict__ deg, int* __restrict__ off,
    int* __restrict__ bsum) {
  __shared__ int wsum[16];
  const int tid = threadIdx.x;
  const int lane = tid & 63;
  const int w = tid >> 6;
  const int i = blockIdx.x * 1024 + tid;
  const int v = (i < NV) ? deg[i] : 0;
  int s = v;
#pragma unroll
  for (int ofs = 1; ofs < 64; ofs <<= 1) {
    int x = __shfl_up(s, ofs, 64);
    if (lane >= ofs) s += x;
  }
  if (lane == 63) wsum[w] = s;
  __syncthreads();
  if (w == 0) {
    int t2 = (lane < 16) ? wsum[lane] : 0;
#pragma unroll
    for (int ofs = 1; ofs < 16; ofs <<= 1) {
      int x = __shfl_up(t2, ofs, 64);
      if (lane >= ofs) t2 += x;
    }
    if (lane < 16) wsum[lane] = t2;
  }
  __syncthreads();
  const int base = (w > 0) ? wsum[w - 1] : 0;
  if (i < NV) off[i] = base + s - v;
  if (tid == 0) bsum[blockIdx.x] = wsum[15];
}

// ------- parallel scan, pass 2 (+ H1 zero-row init) -------------------
__global__ __launch_bounds__(1024) void scan_fix_kernel(
    const int* __restrict__ bsum, int* __restrict__ off,
    unsigned* __restrict__ h1zrow) {
  __shared__ int sbase, stot;
  const int tid = threadIdx.x;
  const int b = blockIdx.x;
  if (b == 0 && tid < 32) h1zrow[tid] = 0u;   // folded memset (128 B)
  if (tid == 0) {
    int acc = 0, tot = 0;
    for (int j = 0; j < NB; j++) {
      const int x = bsum[j];
      if (j < b) acc += x;
      tot += x;
    }
    sbase = acc;
    stot = tot;
  }
  __syncthreads();
  const int i = b * 1024 + tid;
  if (i < NV) off[i] += sbase;
  if (b == NB - 1 && tid == 0) off[NV] = stot;
}

// ------- CSR perm: no atomics, u16 payload, plain store ---------------
__global__ __launch_bounds__(256) void perm_kernel(
    const int* __restrict__ src, const int* __restrict__ dst,
    const unsigned short* __restrict__ rank, const int* __restrict__ off,
    unsigned short* __restrict__ gsrc) {
  const int e = blockIdx.x * 256 + threadIdx.x;
  if (e < EV) {
    const int pos = off[dst[e]] + (int)rank[e];
    gsrc[pos] = (unsigned short)src[e];
  }
}

// ------- fused aggregate + combine, v9 (unchanged from r13) -----------
__global__ __launch_bounds__(256) void aggcomb_kernel(
    const __half* __restrict__ hin, __half* __restrict__ hout,
    const unsigned short* __restrict__ gsrc, const int* __restrict__ off,
    const float* __restrict__ wconv, const float* __restrict__ cb,
    const float* __restrict__ gamma, const float* __restrict__ beta,
    const float* __restrict__ mean, const float* __restrict__ var) {
  __shared__ unsigned sS1[4][4][32];   // wave x slot x 64 halves (2 KB)
  __shared__ unsigned sH[4][4][32];    // wave x slot x 64 halves (2 KB)
  const int wave = threadIdx.x >> 6;
  const int lane = threadIdx.x & 63;
  const int sub = lane >> 4;   // node slot 0..3
  const int q = lane & 15;
  const int r8 = q & 7;        // uint4 slot within row (8 features)
  const int par = q >> 3;      // edge parity
  const int f = lane;          // output feature in combine phase
  unsigned Ws2[32], Wd2[32];
#pragma unroll
  for (int j = 0; j < 32; j++) {
    Ws2[j] = packh2(wconv[(2 * j) * HD + f], wconv[(2 * j + 1) * HD + f]);
    Wd2[j] = packh2(wconv[(HD + 2 * j) * HD + f],
                    wconv[(HD + 2 * j + 1) * HD + f]);
  }
  const float cbf = cb[f];
  const float gf = gamma[f];
  const float btf = beta[f];
  const float mf = mean[f];
  const float inv = rsqrtf(var[f] + 1e-3f);
  const uint4* hp = (const uint4*)hin;   // 8 uint4 per 64-half row
  const int wid = blockIdx.x * 4 + wave;
  const int nw = gridDim.x * 4;
  const int ngroups = NV / 4;            // 12500 exactly
  for (int g = wid; g < ngroups; g += nw) {
    const int n0 = g * 4;
    const int n = n0 + sub;              // this slot's node
    const int j0 = off[n];
    const int deg = off[n + 1] - j0;
    int dm = deg;                        // wave-max degree
    dm = max(dm, __shfl_xor(dm, 16, 64));
    dm = max(dm, __shfl_xor(dm, 32, 64));
    const uint4 hrv = hp[(size_t)n * 8 + r8];     // own row (par dup ok)
    float a0 = 0.f, a1 = 0.f, a2 = 0.f, a3 = 0.f;
    float a4 = 0.f, a5 = 0.f, a6 = 0.f, a7 = 0.f;
    for (int base = 0; base < dm; base += 16) {
      const int e = base + q;
      const int eid = (e < deg) ? (int)gsrc[j0 + e] : NV;  // NV = zero row
#pragma unroll
      for (int i = 0; i < 8; i++) {
        const int a = __shfl(eid, (sub << 4) | (2 * i + par), 64);
        const uint4 v = hp[(size_t)a * 8 + r8];
        const __half2 p0 = *(const __half2*)&v.x;
        const __half2 p1 = *(const __half2*)&v.y;
        const __half2 p2 = *(const __half2*)&v.z;
        const __half2 p3 = *(const __half2*)&v.w;
        a0 += __low2float(p0);  a1 += __high2float(p0);
        a2 += __low2float(p1);  a3 += __high2float(p1);
        a4 += __low2float(p2);  a5 += __high2float(p2);
        a6 += __low2float(p3);  a7 += __high2float(p3);
      }
    }
    // parity combine (lanes q and q^8 hold same features, disjoint edges)
    a0 += __shfl_xor(a0, 8, 64); a1 += __shfl_xor(a1, 8, 64);
    a2 += __shfl_xor(a2, 8, 64); a3 += __shfl_xor(a3, 8, 64);
    a4 += __shfl_xor(a4, 8, 64); a5 += __shfl_xor(a5, 8, 64);
    a6 += __shfl_xor(a6, 8, 64); a7 += __shfl_xor(a7, 8, 64);
    // hand-off via wave-private LDS, packed fp16 (no barrier)
    if (par == 0) {
      uint4 s1p;
      s1p.x = packh2(a0, a1); s1p.y = packh2(a2, a3);
      s1p.z = packh2(a4, a5); s1p.w = packh2(a6, a7);
      ((uint4*)sS1[wave][sub])[r8] = s1p;
      ((uint4*)sH[wave][sub])[r8] = hrv;          // already fp16
    }
#pragma unroll
    for (int m4 = 0; m4 < 4; m4++) {
      const uint4* s1p = (const uint4*)sS1[wave][m4];
      const uint4* hq = (const uint4*)sH[wave][m4];
      float b1a = 0.f, b1b = 0.f, b2a = 0.f, b2b = 0.f;
#pragma unroll
      for (int t = 0; t < 8; t++) {      // k8 blocks, uniform broadcasts
        const uint4 xs = s1p[t];
        const uint4 xh = hq[t];
        b1a = dot2acc(xs.x, Ws2[4 * t + 0], b1a);
        b1b = dot2acc(xs.y, Ws2[4 * t + 1], b1b);
        b1a = dot2acc(xs.z, Ws2[4 * t + 2], b1a);
        b1b = dot2acc(xs.w, Ws2[4 * t + 3], b1b);
        b2a = dot2acc(xh.x, Wd2[4 * t + 0], b2a);
        b2b = dot2acc(xh.y, Wd2[4 * t + 1], b2b);
        b2a = dot2acc(xh.z, Wd2[4 * t + 2], b2a);
        b2b = dot2acc(xh.w, Wd2[4 * t + 3], b2b);
      }
      const float s1w = b1a + b1b;
      const float hw = b2a + b2b;
      const float hvf =
          __half2float(((const __half*)sH[wave][m4])[f]);  // 2-way: free
      const float d = (float)__shfl(deg, m4 << 4, 64);
      const float agg = s1w + d * hw + d * cbf;
      const float sig = 1.f / (1.f + __expf(-agg));
      const float sp = fmaxf(hvf, 0.f) + log1pf(__expf(-fabsf(hvf)));
      float x = sig + sp;
      x = gf * (x - mf) * inv + btf;
      hout[(size_t)(n0 + m4) * HD + f] = __float2half_rn(fmaxf(x, 0.f));
    }
  }
}

// ------- scores v5: 2 edges/group + pinned load cluster ---------------
// r14's 2-edge version compiled to VGPR=36 — the compiler serialized
// the two edges' load/consume phases, so MLP never rose. sched_barrier(0)
// after the 14 gathers forces all loads to issue before any consume
// (live ranges -> VGPR ~90, 14 outstanding misses per thread).
__global__ __launch_bounds__(256) void score_kernel(
    const __half* __restrict__ hh, const int* __restrict__ src,
    const int* __restrict__ dst, const int* __restrict__ neg_dst,
    const float* __restrict__ wrel, float* __restrict__ out) {
  const int tid = blockIdx.x * 256 + threadIdx.x;
  const int gid = tid >> 3;     // edge-pair group
  const int q = tid & 7;
  const int eA = gid * 2;
  if (eA >= EV) return;
  const int eB = eA + 1;
  const int lane = threadIdx.x & 63;
  const int base8 = lane & 56;  // first lane of this group
  const float4 w0 = ((const float4*)wrel)[2 * q];
  const float4 w1 = ((const float4*)wrel)[2 * q + 1];
  const __half2 wh0 = __floats2half2_rn(w0.x, w0.y);
  const __half2 wh1 = __floats2half2_rn(w0.z, w0.w);
  const __half2 wh2 = __floats2half2_rn(w1.x, w1.y);
  const __half2 wh3 = __floats2half2_rn(w1.z, w1.w);

  // two index loads per lane, by role (q: 0=src,1=dst,2..6=neg,7=dup)
  const int* ipA = (q == 0) ? (src + eA)
                 : (q == 1) ? (dst + eA)
                            : (neg_dst + (size_t)eA * KNEG + min(q - 2, KNEG - 1));
  const int* ipB = (q == 0) ? (src + eB)
                 : (q == 1) ? (dst + eB)
                            : (neg_dst + (size_t)eB * KNEG + min(q - 2, KNEG - 1));
  const int myA = *ipA;
  const int myB = *ipB;
  const int sA = __shfl(myA, base8 + 0, 64);
  const int dA = __shfl(myA, base8 + 1, 64);
  const int sB = __shfl(myB, base8 + 0, 64);
  const int dB = __shfl(myB, base8 + 1, 64);
  int ndA[KNEG], ndB[KNEG];
#pragma unroll
  for (int r = 0; r < KNEG; r++) {
    ndA[r] = __shfl(myA, base8 + 2 + r, 64);
    ndB[r] = __shfl(myB, base8 + 2 + r, 64);
  }
  __builtin_amdgcn_sched_barrier(0);   // addresses formed; now the loads

  const uint4* hp = (const uint4*)hh;
  // issue all 14 gathers — nothing may sink below the next fence
  const uint4 svA = hp[(size_t)sA * 8 + q];
  const uint4 dvA = hp[(size_t)dA * 8 + q];
  const uint4 svB = hp[(size_t)sB * 8 + q];
  const uint4 dvB = hp[(size_t)dB * 8 + q];
  uint4 nvA[KNEG], nvB[KNEG];
#pragma unroll
  for (int r = 0; r < KNEG; r++) {
    nvA[r] = hp[(size_t)ndA[r] * 8 + q];
    nvB[r] = hp[(size_t)ndB[r] * 8 + q];
  }
  __builtin_amdgcn_sched_barrier(0);   // all 14 loads issued above

#define AW(sv, a0, a1, a2, a3)                                        \
  const unsigned a0 = __builtin_bit_cast(unsigned,                    \
      __hmul2(*(const __half2*)&sv.x, wh0));                          \
  const unsigned a1 = __builtin_bit_cast(unsigned,                    \
      __hmul2(*(const __half2*)&sv.y, wh1));                          \
  const unsigned a2 = __builtin_bit_cast(unsigned,                    \
      __hmul2(*(const __half2*)&sv.z, wh2));                          \
  const unsigned a3 = __builtin_bit_cast(unsigned,                    \
      __hmul2(*(const __half2*)&sv.w, wh3));
  AW(svA, aA0, aA1, aA2, aA3)
  AW(svB, aB0, aB1, aB2, aB3)
#undef AW
#define DOT(a0, a1, a2, a3, v)                                        \
  dot2acc(a3, v.w, dot2acc(a2, v.z, dot2acc(a1, v.y, dot2acc(a0, v.x, 0.f))))

  float uA0 = DOT(aA0, aA1, aA2, aA3, dvA);
  float uA1 = DOT(aA0, aA1, aA2, aA3, nvA[0]);
  float uA2 = DOT(aA0, aA1, aA2, aA3, nvA[1]);
  float uA3 = DOT(aA0, aA1, aA2, aA3, nvA[2]);
  float uA4 = DOT(aA0, aA1, aA2, aA3, nvA[3]);
  float uA5 = DOT(aA0, aA1, aA2, aA3, nvA[4]);
  float uB0 = DOT(aB0, aB1, aB2, aB3, dvB);
  float uB1 = DOT(aB0, aB1, aB2, aB3, nvB[0]);
  float uB2 = DOT(aB0, aB1, aB2, aB3, nvB[1]);
  float uB3 = DOT(aB0, aB1, aB2, aB3, nvB[2]);
  float uB4 = DOT(aB0, aB1, aB2, aB3, nvB[3]);
  float uB5 = DOT(aB0, aB1, aB2, aB3, nvB[4]);
#undef DOT

  // joint reduce-scatter (per edge): lane q ends with score q
#define RSCAT(v0, v1, v2, v3, v4, v5)                                 \
  {                                                                   \
    const bool hi = (q & 4) != 0;                                     \
    float t0 = hi ? v0 : v4, t1 = hi ? v1 : v5;                       \
    float t2 = hi ? v2 : 0.f, t3 = hi ? v3 : 0.f;                     \
    t0 = __shfl_xor(t0, 4, 64); t1 = __shfl_xor(t1, 4, 64);           \
    t2 = __shfl_xor(t2, 4, 64); t3 = __shfl_xor(t3, 4, 64);           \
    v0 = (hi ? v4 : v0) + t0;                                         \
    v1 = (hi ? v5 : v1) + t1;                                         \
    v2 = (hi ? 0.f : v2) + t2;                                        \
    v3 = (hi ? 0.f : v3) + t3;                                        \
  }                                                                   \
  {                                                                   \
    const bool hi = (q & 2) != 0;                                     \
    float t0 = hi ? v0 : v2, t1 = hi ? v1 : v3;                       \
    t0 = __shfl_xor(t0, 2, 64); t1 = __shfl_xor(t1, 2, 64);           \
    v0 = (hi ? v2 : v0) + t0;                                         \
    v1 = (hi ? v3 : v1) + t1;                                         \
  }                                                                   \
  {                                                                   \
    const bool hi = (q & 1) != 0;                                     \
    float t0 = hi ? v0 : v1;                                          \
    t0 = __shfl_xor(t0, 1, 64);                                       \
    v0 = (hi ? v1 : v0) + t0;                                         \
  }
  RSCAT(uA0, uA1, uA2, uA3, uA4, uA5)
  RSCAT(uB0, uB1, uB2, uB3, uB4, uB5)
#undef RSCAT

  // out is never re-read: nontemporal avoids write-allocate in L2
  if (q == 0) {
    __builtin_nontemporal_store(uA0, &out[eA]);
    __builtin_nontemporal_store(uB0, &out[eB]);
  } else if (q <= KNEG) {
    __builtin_nontemporal_store(
        uA0, &out[(size_t)EV + (size_t)eA * KNEG + (q - 1)]);
    __builtin_nontemporal_store(
        uB0, &out[(size_t)EV + (size_t)eB * KNEG + (q - 1)]);
  }
}

extern "C" void kernel_launch(void* const* d_in, const int* in_sizes, int n_in,
                              void* d_out, int out_size, void* d_ws, size_t ws_size,
                              hipStream_t stream) {
  const float* node_feat = (const float*)d_in[0];
  const float* emb_w     = (const float*)d_in[1];
  const float* emb_b     = (const float*)d_in[2];
  const float* conv_w    = (const float*)d_in[3];
  const float* conv_b    = (const float*)d_in[4];
  const float* bn_gamma  = (const float*)d_in[5];
  const float* bn_beta   = (const float*)d_in[6];
  const float* bn_mean   = (const float*)d_in[7];
  const float* bn_var    = (const float*)d_in[8];
  const float* w_rel     = (const float*)d_in[9];
  const int*   src       = (const int*)d_in[10];
  const int*   dst       = (const int*)d_in[11];
  const int*   neg_dst   = (const int*)d_in[12];
  float* out = (float*)d_out;

  // ws layout: H0 | H1 (each NV+1 rows; row NV = zeros) | off | gsrc | bsum
  __half* H0 = (__half*)d_ws;                        // (NV+1) x HD fp16
  __half* H1 = H0 + (size_t)(NV + 1) * HD;
  int*   off  = (int*)(H1 + (size_t)(NV + 1) * HD);
  unsigned short* gsrc = (unsigned short*)(off + (NV + 1));
  int*   bsum = (int*)(gsrc + EV);
  int*   deg  = (int*)H1;
  unsigned short* rank = ((unsigned short*)H1) + 2 * NV;

  hipMemsetAsync(deg, 0, (size_t)NV * sizeof(int), stream);
  embed_hist_kernel<<<1024, 256, 0, stream>>>(node_feat, emb_w, emb_b, H0,
                                              dst, deg, rank);
  scan_part_kernel<<<NB, 1024, 0, stream>>>(deg, off, bsum);
  scan_fix_kernel<<<NB, 1024, 0, stream>>>(bsum, off,
                                           (unsigned*)(H1 + (size_t)NV * HD));
  perm_kernel<<<(EV + 255) / 256, 256, 0, stream>>>(src, dst, rank, off, gsrc);

  // layer 0: H0 -> H1 ; layer 1: H1 -> H0  (ping-pong)
  aggcomb_kernel<<<1024, 256, 0, stream>>>(
      H0, H1, gsrc, off, conv_w, conv_b,
      bn_gamma, bn_beta, bn_mean, bn_var);
  aggcomb_kernel<<<1024, 256, 0, stream>>>(
      H1, H0, gsrc, off, conv_w + 2 * HD * HD, conv_b + HD,
      bn_gamma + HD, bn_beta + HD, bn_mean + HD, bn_var + HD);

  score_kernel<<<(EV / 2 * 8 + 255) / 256, 256, 0, stream>>>(
      H0, src, dst, neg_dst, w_rel, out);
}

// Round 16
// 292.800 us; speedup vs baseline: 1.0125x; 1.0125x over previous
//
#include <hip/hip_runtime.h>
#include <hip/hip_fp16.h>

#define NV 50000
#define EV 800000
#define INF 128
#define HD 64
#define KNEG 5
#define NB ((NV + 1023) / 1024)   // 49 scan blocks

#if defined(__has_builtin)
#if __has_builtin(__builtin_amdgcn_fdot2)
#define HAS_FDOT2 1
#endif
#endif

typedef _Float16 half2r __attribute__((ext_vector_type(2)));

// dot2: c += a.lo*b.lo + a.hi*b.hi  (f16 pairs, f32 accumulate)
__device__ __forceinline__ float dot2acc(unsigned a, unsigned b, float c) {
#ifdef HAS_FDOT2
  return __builtin_amdgcn_fdot2(__builtin_bit_cast(half2r, a),
                                __builtin_bit_cast(half2r, b), c, false);
#else
  const __half2 ha = *(const __half2*)&a;
  const __half2 hb = *(const __half2*)&b;
  return c + __low2float(ha) * __low2float(hb)
           + __high2float(ha) * __high2float(hb);
#endif
}

__device__ __forceinline__ unsigned packh2(float lo, float hi) {
  return __builtin_bit_cast(unsigned, __floats2half2_rn(lo, hi));
}

// pinned 16B global load: asm volatile keeps program order; RA must give
// each load a distinct destination quad -> the cluster stays in flight.
__device__ __forceinline__ uint4 gload16(const uint4* p) {
  uint4 r;
  asm volatile("global_load_dwordx4 %0, %1, off" : "=v"(r) : "v"(p));
  return r;
}

// ------- embed + hist fused, v6b (unchanged from r13) -----------------
__global__ __launch_bounds__(256) void embed_hist_kernel(
    const float* __restrict__ feat, const float* __restrict__ W,
    const float* __restrict__ b, __half* __restrict__ h,
    const int* __restrict__ dst, int* __restrict__ deg,
    unsigned short* __restrict__ rank) {
  __shared__ unsigned sF[4][2][256];   // wave x buf x 512 halves = 8 KB
  const int lane = threadIdx.x & 63;
  const int wave = threadIdx.x >> 6;
  // zero row NV of h (gather's out-of-degree target) — folded memset
  if (blockIdx.x == 0 && threadIdx.x < 32)
    ((unsigned*)(h + (size_t)NV * HD))[threadIdx.x] = 0u;
  unsigned Wh[64];
#pragma unroll
  for (int j = 0; j < 64; j++)
    Wh[j] = packh2(W[(2 * j) * HD + lane], W[(2 * j + 1) * HD + lane]);
  const float bias = b[lane];
  const int nwaves = gridDim.x * 4;
  const int wid = blockIdx.x * 4 + wave;   // wave-uniform
  const int ngroups = NV / 4;              // 12500 exactly

  int buf = 0;
  int g = wid;
  if (g < ngroups) {
    const float4* gp = (const float4*)(feat + (size_t)g * 512);
    const float4 a0 = gp[lane];
    const float4 a1 = gp[lane + 64];
    uint2 c0, c1;
    c0.x = packh2(a0.x, a0.y); c0.y = packh2(a0.z, a0.w);
    c1.x = packh2(a1.x, a1.y); c1.y = packh2(a1.z, a1.w);
    ((uint2*)sF[wave][0])[lane] = c0;
    ((uint2*)sF[wave][0])[lane + 64] = c1;
  }
  for (; g < ngroups; g += nwaves) {
    const int gn = g + nwaves;
    float4 b0, b1;
    if (gn < ngroups) {                    // wave-uniform guard
      const float4* gp = (const float4*)(feat + (size_t)gn * 512);
      b0 = gp[lane];                       // prefetch next group
      b1 = gp[lane + 64];
    }
    float acc0 = bias, acc1 = bias, acc2 = bias, acc3 = bias;
    const uint4* F = (const uint4*)sF[wave][buf];
#pragma unroll
    for (int t = 0; t < 16; t++) {         // k8 blocks
      const uint4 x0 = F[t];               // broadcast reads (uniform)
      const uint4 x1 = F[16 + t];
      const uint4 x2 = F[32 + t];
      const uint4 x3 = F[48 + t];
      const unsigned w0 = Wh[4 * t + 0];
      const unsigned w1 = Wh[4 * t + 1];
      const unsigned w2 = Wh[4 * t + 2];
      const unsigned w3 = Wh[4 * t + 3];
      acc0 = dot2acc(x0.x, w0, acc0); acc0 = dot2acc(x0.y, w1, acc0);
      acc0 = dot2acc(x0.z, w2, acc0); acc0 = dot2acc(x0.w, w3, acc0);
      acc1 = dot2acc(x1.x, w0, acc1); acc1 = dot2acc(x1.y, w1, acc1);
      acc1 = dot2acc(x1.z, w2, acc1); acc1 = dot2acc(x1.w, w3, acc1);
      acc2 = dot2acc(x2.x, w0, acc2); acc2 = dot2acc(x2.y, w1, acc2);
      acc2 = dot2acc(x2.z, w2, acc2); acc2 = dot2acc(x2.w, w3, acc2);
      acc3 = dot2acc(x3.x, w0, acc3); acc3 = dot2acc(x3.y, w1, acc3);
      acc3 = dot2acc(x3.z, w2, acc3); acc3 = dot2acc(x3.w, w3, acc3);
    }
    __half* hpo = h + (size_t)g * 256 + lane;   // 4 coalesced 128B stores
    hpo[0]   = __float2half_rn(acc0);
    hpo[64]  = __float2half_rn(acc1);
    hpo[128] = __float2half_rn(acc2);
    hpo[192] = __float2half_rn(acc3);
    if (gn < ngroups) {
      uint2 c0, c1;
      c0.x = packh2(b0.x, b0.y); c0.y = packh2(b0.z, b0.w);
      c1.x = packh2(b1.x, b1.y); c1.y = packh2(b1.z, b1.w);
      ((uint2*)sF[wave][buf ^ 1])[lane] = c0;
      ((uint2*)sF[wave][buf ^ 1])[lane + 64] = c1;
      buf ^= 1;
    }
  }
  // hist tail: overlaps with GEMM-bound waves of other blocks
  for (int e = blockIdx.x * 256 + threadIdx.x; e < EV; e += gridDim.x * 256) {
    const int r = atomicAdd(&deg[dst[e]], 1);
    rank[e] = (unsigned short)r;             // coalesced u16 store
  }
}

// ------- parallel scan, pass 1 ----------------------------------------
__global__ __launch_bounds__(1024) void scan_part_kernel(
    const int* __restrict__ deg, int* __restrict__ off,
    int* __restrict__ bsum) {
  __shared__ int wsum[16];
  const int tid = threadIdx.x;
  const int lane = tid & 63;
  const int w = tid >> 6;
  const int i = blockIdx.x * 1024 + tid;
  const int v = (i < NV) ? deg[i] : 0;
  int s = v;
#pragma unroll
  for (int ofs = 1; ofs < 64; ofs <<= 1) {
    int x = __shfl_up(s, ofs, 64);
    if (lane >= ofs) s += x;
  }
  if (lane == 63) wsum[w] = s;
  __syncthreads();
  if (w == 0) {
    int t2 = (lane < 16) ? wsum[lane] : 0;
#pragma unroll
    for (int ofs = 1; ofs < 16; ofs <<= 1) {
      int x = __shfl_up(t2, ofs, 64);
      if (lane >= ofs) t2 += x;
    }
    if (lane < 16) wsum[lane] = t2;
  }
  __syncthreads();
  const int base = (w > 0) ? wsum[w - 1] : 0;
  if (i < NV) off[i] = base + s - v;
  if (tid == 0) bsum[blockIdx.x] = wsum[15];
}

// ------- parallel scan, pass 2 (+ H1 zero-row init) -------------------
__global__ __launch_bounds__(1024) void scan_fix_kernel(
    const int* __restrict__ bsum, int* __restrict__ off,
    unsigned* __restrict__ h1zrow) {
  __shared__ int sbase, stot;
  const int tid = threadIdx.x;
  const int b = blockIdx.x;
  if (b == 0 && tid < 32) h1zrow[tid] = 0u;   // folded memset (128 B)
  if (tid == 0) {
    int acc = 0, tot = 0;
    for (int j = 0; j < NB; j++) {
      const int x = bsum[j];
      if (j < b) acc += x;
      tot += x;
    }
    sbase = acc;
    stot = tot;
  }
  __syncthreads();
  const int i = b * 1024 + tid;
  if (i < NV) off[i] += sbase;
  if (b == NB - 1 && tid == 0) off[NV] = stot;
}

// ------- CSR perm: no atomics, u16 payload, plain store ---------------
__global__ __launch_bounds__(256) void perm_kernel(
    const int* __restrict__ src, const int* __restrict__ dst,
    const unsigned short* __restrict__ rank, const int* __restrict__ off,
    unsigned short* __restrict__ gsrc) {
  const int e = blockIdx.x * 256 + threadIdx.x;
  if (e < EV) {
    const int pos = off[dst[e]] + (int)rank[e];
    gsrc[pos] = (unsigned short)src[e];
  }
}

// ------- fused aggregate + combine, v9 (unchanged from r13) -----------
__global__ __launch_bounds__(256) void aggcomb_kernel(
    const __half* __restrict__ hin, __half* __restrict__ hout,
    const unsigned short* __restrict__ gsrc, const int* __restrict__ off,
    const float* __restrict__ wconv, const float* __restrict__ cb,
    const float* __restrict__ gamma, const float* __restrict__ beta,
    const float* __restrict__ mean, const float* __restrict__ var) {
  __shared__ unsigned sS1[4][4][32];   // wave x slot x 64 halves (2 KB)
  __shared__ unsigned sH[4][4][32];    // wave x slot x 64 halves (2 KB)
  const int wave = threadIdx.x >> 6;
  const int lane = threadIdx.x & 63;
  const int sub = lane >> 4;   // node slot 0..3
  const int q = lane & 15;
  const int r8 = q & 7;        // uint4 slot within row (8 features)
  const int par = q >> 3;      // edge parity
  const int f = lane;          // output feature in combine phase
  unsigned Ws2[32], Wd2[32];
#pragma unroll
  for (int j = 0; j < 32; j++) {
    Ws2[j] = packh2(wconv[(2 * j) * HD + f], wconv[(2 * j + 1) * HD + f]);
    Wd2[j] = packh2(wconv[(HD + 2 * j) * HD + f],
                    wconv[(HD + 2 * j + 1) * HD + f]);
  }
  const float cbf = cb[f];
  const float gf = gamma[f];
  const float btf = beta[f];
  const float mf = mean[f];
  const float inv = rsqrtf(var[f] + 1e-3f);
  const uint4* hp = (const uint4*)hin;   // 8 uint4 per 64-half row
  const int wid = blockIdx.x * 4 + wave;
  const int nw = gridDim.x * 4;
  const int ngroups = NV / 4;            // 12500 exactly
  for (int g = wid; g < ngroups; g += nw) {
    const int n0 = g * 4;
    const int n = n0 + sub;              // this slot's node
    const int j0 = off[n];
    const int deg = off[n + 1] - j0;
    int dm = deg;                        // wave-max degree
    dm = max(dm, __shfl_xor(dm, 16, 64));
    dm = max(dm, __shfl_xor(dm, 32, 64));
    const uint4 hrv = hp[(size_t)n * 8 + r8];     // own row (par dup ok)
    float a0 = 0.f, a1 = 0.f, a2 = 0.f, a3 = 0.f;
    float a4 = 0.f, a5 = 0.f, a6 = 0.f, a7 = 0.f;
    for (int base = 0; base < dm; base += 16) {
      const int e = base + q;
      const int eid = (e < deg) ? (int)gsrc[j0 + e] : NV;  // NV = zero row
#pragma unroll
      for (int i = 0; i < 8; i++) {
        const int a = __shfl(eid, (sub << 4) | (2 * i + par), 64);
        const uint4 v = hp[(size_t)a * 8 + r8];
        const __half2 p0 = *(const __half2*)&v.x;
        const __half2 p1 = *(const __half2*)&v.y;
        const __half2 p2 = *(const __half2*)&v.z;
        const __half2 p3 = *(const __half2*)&v.w;
        a0 += __low2float(p0);  a1 += __high2float(p0);
        a2 += __low2float(p1);  a3 += __high2float(p1);
        a4 += __low2float(p2);  a5 += __high2float(p2);
        a6 += __low2float(p3);  a7 += __high2float(p3);
      }
    }
    // parity combine (lanes q and q^8 hold same features, disjoint edges)
    a0 += __shfl_xor(a0, 8, 64); a1 += __shfl_xor(a1, 8, 64);
    a2 += __shfl_xor(a2, 8, 64); a3 += __shfl_xor(a3, 8, 64);
    a4 += __shfl_xor(a4, 8, 64); a5 += __shfl_xor(a5, 8, 64);
    a6 += __shfl_xor(a6, 8, 64); a7 += __shfl_xor(a7, 8, 64);
    // hand-off via wave-private LDS, packed fp16 (no barrier)
    if (par == 0) {
      uint4 s1p;
      s1p.x = packh2(a0, a1); s1p.y = packh2(a2, a3);
      s1p.z = packh2(a4, a5); s1p.w = packh2(a6, a7);
      ((uint4*)sS1[wave][sub])[r8] = s1p;
      ((uint4*)sH[wave][sub])[r8] = hrv;          // already fp16
    }
#pragma unroll
    for (int m4 = 0; m4 < 4; m4++) {
      const uint4* s1p = (const uint4*)sS1[wave][m4];
      const uint4* hq = (const uint4*)sH[wave][m4];
      float b1a = 0.f, b1b = 0.f, b2a = 0.f, b2b = 0.f;
#pragma unroll
      for (int t = 0; t < 8; t++) {      // k8 blocks, uniform broadcasts
        const uint4 xs = s1p[t];
        const uint4 xh = hq[t];
        b1a = dot2acc(xs.x, Ws2[4 * t + 0], b1a);
        b1b = dot2acc(xs.y, Ws2[4 * t + 1], b1b);
        b1a = dot2acc(xs.z, Ws2[4 * t + 2], b1a);
        b1b = dot2acc(xs.w, Ws2[4 * t + 3], b1b);
        b2a = dot2acc(xh.x, Wd2[4 * t + 0], b2a);
        b2b = dot2acc(xh.y, Wd2[4 * t + 1], b2b);
        b2a = dot2acc(xh.z, Wd2[4 * t + 2], b2a);
        b2b = dot2acc(xh.w, Wd2[4 * t + 3], b2b);
      }
      const float s1w = b1a + b1b;
      const float hw = b2a + b2b;
      const float hvf =
          __half2float(((const __half*)sH[wave][m4])[f]);  // 2-way: free
      const float d = (float)__shfl(deg, m4 << 4, 64);
      const float agg = s1w + d * hw + d * cbf;
      const float sig = 1.f / (1.f + __expf(-agg));
      const float sp = fmaxf(hvf, 0.f) + log1pf(__expf(-fabsf(hvf)));
      float x = sig + sp;
      x = gf * (x - mf) * inv + btf;
      hout[(size_t)(n0 + m4) * HD + f] = __float2half_rn(fmaxf(x, 0.f));
    }
  }
}

// ------- scores v6: 2 edges/group, asm-pinned 14-load cluster ---------
// r14/r15: the compiler refused to keep the 14 gathers in flight (VGPR
// stayed 36; sched_barrier didn't pin). asm volatile global_load forces
// program-order issue into 14 distinct dest quads; one manual
// s_waitcnt vmcnt(0) + sched_barrier(0) (rule #18) before any consume.
__global__ __launch_bounds__(256) void score_kernel(
    const __half* __restrict__ hh, const int* __restrict__ src,
    const int* __restrict__ dst, const int* __restrict__ neg_dst,
    const float* __restrict__ wrel, float* __restrict__ out) {
  const int tid = blockIdx.x * 256 + threadIdx.x;
  const int gid = tid >> 3;     // edge-pair group
  const int q = tid & 7;
  const int eA = gid * 2;
  if (eA >= EV) return;
  const int eB = eA + 1;
  const int lane = threadIdx.x & 63;
  const int base8 = lane & 56;  // first lane of this group
  const float4 w0 = ((const float4*)wrel)[2 * q];
  const float4 w1 = ((const float4*)wrel)[2 * q + 1];
  const __half2 wh0 = __floats2half2_rn(w0.x, w0.y);
  const __half2 wh1 = __floats2half2_rn(w0.z, w0.w);
  const __half2 wh2 = __floats2half2_rn(w1.x, w1.y);
  const __half2 wh3 = __floats2half2_rn(w1.z, w1.w);

  // two index loads per lane, by role (q: 0=src,1=dst,2..6=neg,7=dup)
  const int* ipA = (q == 0) ? (src + eA)
                 : (q == 1) ? (dst + eA)
                            : (neg_dst + (size_t)eA * KNEG + min(q - 2, KNEG - 1));
  const int* ipB = (q == 0) ? (src + eB)
                 : (q == 1) ? (dst + eB)
                            : (neg_dst + (size_t)eB * KNEG + min(q - 2, KNEG - 1));
  const int myA = *ipA;
  const int myB = *ipB;
  const int sA = __shfl(myA, base8 + 0, 64);
  const int dA = __shfl(myA, base8 + 1, 64);
  const int sB = __shfl(myB, base8 + 0, 64);
  const int dB = __shfl(myB, base8 + 1, 64);
  int ndA[KNEG], ndB[KNEG];
#pragma unroll
  for (int r = 0; r < KNEG; r++) {
    ndA[r] = __shfl(myA, base8 + 2 + r, 64);
    ndB[r] = __shfl(myB, base8 + 2 + r, 64);
  }

  const uint4* hp = (const uint4*)hh;
  // pinned 14-load cluster: all issue before the waitcnt below
  const uint4 svA = gload16(hp + (size_t)sA * 8 + q);
  const uint4 dvA = gload16(hp + (size_t)dA * 8 + q);
  const uint4 svB = gload16(hp + (size_t)sB * 8 + q);
  const uint4 dvB = gload16(hp + (size_t)dB * 8 + q);
  uint4 nvA[KNEG], nvB[KNEG];
#pragma unroll
  for (int r = 0; r < KNEG; r++) {
    nvA[r] = gload16(hp + (size_t)ndA[r] * 8 + q);
    nvB[r] = gload16(hp + (size_t)ndB[r] * 8 + q);
  }
  asm volatile("s_waitcnt vmcnt(0)" ::: "memory");
  __builtin_amdgcn_sched_barrier(0);   // rule #18: no consumer hoisting

#define AW(sv, a0, a1, a2, a3)                                        \
  const unsigned a0 = __builtin_bit_cast(unsigned,                    \
      __hmul2(*(const __half2*)&sv.x, wh0));                          \
  const unsigned a1 = __builtin_bit_cast(unsigned,                    \
      __hmul2(*(const __half2*)&sv.y, wh1));                          \
  const unsigned a2 = __builtin_bit_cast(unsigned,                    \
      __hmul2(*(const __half2*)&sv.z, wh2));                          \
  const unsigned a3 = __builtin_bit_cast(unsigned,                    \
      __hmul2(*(const __half2*)&sv.w, wh3));
  AW(svA, aA0, aA1, aA2, aA3)
  AW(svB, aB0, aB1, aB2, aB3)
#undef AW
#define DOT(a0, a1, a2, a3, v)                                        \
  dot2acc(a3, v.w, dot2acc(a2, v.z, dot2acc(a1, v.y, dot2acc(a0, v.x, 0.f))))

  float uA0 = DOT(aA0, aA1, aA2, aA3, dvA);
  float uA1 = DOT(aA0, aA1, aA2, aA3, nvA[0]);
  float uA2 = DOT(aA0, aA1, aA2, aA3, nvA[1]);
  float uA3 = DOT(aA0, aA1, aA2, aA3, nvA[2]);
  float uA4 = DOT(aA0, aA1, aA2, aA3, nvA[3]);
  float uA5 = DOT(aA0, aA1, aA2, aA3, nvA[4]);
  float uB0 = DOT(aB0, aB1, aB2, aB3, dvB);
  float uB1 = DOT(aB0, aB1, aB2, aB3, nvB[0]);
  float uB2 = DOT(aB0, aB1, aB2, aB3, nvB[1]);
  float uB3 = DOT(aB0, aB1, aB2, aB3, nvB[2]);
  float uB4 = DOT(aB0, aB1, aB2, aB3, nvB[3]);
  float uB5 = DOT(aB0, aB1, aB2, aB3, nvB[4]);
#undef DOT

  // joint reduce-scatter (per edge): lane q ends with score q
#define RSCAT(v0, v1, v2, v3, v4, v5)                                 \
  {                                                                   \
    const bool hi = (q & 4) != 0;                                     \
    float t0 = hi ? v0 : v4, t1 = hi ? v1 : v5;                       \
    float t2 = hi ? v2 : 0.f, t3 = hi ? v3 : 0.f;                     \
    t0 = __shfl_xor(t0, 4, 64); t1 = __shfl_xor(t1, 4, 64);           \
    t2 = __shfl_xor(t2, 4, 64); t3 = __shfl_xor(t3, 4, 64);           \
    v0 = (hi ? v4 : v0) + t0;                                         \
    v1 = (hi ? v5 : v1) + t1;                                         \
    v2 = (hi ? 0.f : v2) + t2;                                        \
    v3 = (hi ? 0.f : v3) + t3;                                        \
  }                                                                   \
  {                                                                   \
    const bool hi = (q & 2) != 0;                                     \
    float t0 = hi ? v0 : v2, t1 = hi ? v1 : v3;                       \
    t0 = __shfl_xor(t0, 2, 64); t1 = __shfl_xor(t1, 2, 64);           \
    v0 = (hi ? v2 : v0) + t0;                                         \
    v1 = (hi ? v3 : v1) + t1;                                         \
  }                                                                   \
  {                                                                   \
    const bool hi = (q & 1) != 0;                                     \
    float t0 = hi ? v0 : v1;                                          \
    t0 = __shfl_xor(t0, 1, 64);                                       \
    v0 = (hi ? v1 : v0) + t0;                                         \
  }
  RSCAT(uA0, uA1, uA2, uA3, uA4, uA5)
  RSCAT(uB0, uB1, uB2, uB3, uB4, uB5)
#undef RSCAT

  // out is never re-read: nontemporal avoids write-allocate in L2
  if (q == 0) {
    __builtin_nontemporal_store(uA0, &out[eA]);
    __builtin_nontemporal_store(uB0, &out[eB]);
  } else if (q <= KNEG) {
    __builtin_nontemporal_store(
        uA0, &out[(size_t)EV + (size_t)eA * KNEG + (q - 1)]);
    __builtin_nontemporal_store(
        uB0, &out[(size_t)EV + (size_t)eB * KNEG + (q - 1)]);
  }
}

extern "C" void kernel_launch(void* const* d_in, const int* in_sizes, int n_in,
                              void* d_out, int out_size, void* d_ws, size_t ws_size,
                              hipStream_t stream) {
  const float* node_feat = (const float*)d_in[0];
  const float* emb_w     = (const float*)d_in[1];
  const float* emb_b     = (const float*)d_in[2];
  const float* conv_w    = (const float*)d_in[3];
  const float* conv_b    = (const float*)d_in[4];
  const float* bn_gamma  = (const float*)d_in[5];
  const float* bn_beta   = (const float*)d_in[6];
  const float* bn_mean   = (const float*)d_in[7];
  const float* bn_var    = (const float*)d_in[8];
  const float* w_rel     = (const float*)d_in[9];
  const int*   src       = (const int*)d_in[10];
  const int*   dst       = (const int*)d_in[11];
  const int*   neg_dst   = (const int*)d_in[12];
  float* out = (float*)d_out;

  // ws layout: H0 | H1 (each NV+1 rows; row NV = zeros) | off | gsrc | bsum
  __half* H0 = (__half*)d_ws;                        // (NV+1) x HD fp16
  __half* H1 = H0 + (size_t)(NV + 1) * HD;
  int*   off  = (int*)(H1 + (size_t)(NV + 1) * HD);
  unsigned short* gsrc = (unsigned short*)(off + (NV + 1));
  int*   bsum = (int*)(gsrc + EV);
  int*   deg  = (int*)H1;
  unsigned short* rank = ((unsigned short*)H1) + 2 * NV;

  hipMemsetAsync(deg, 0, (size_t)NV * sizeof(int), stream);
  embed_hist_kernel<<<1024, 256, 0, stream>>>(node_feat, emb_w, emb_b, H0,
                                              dst, deg, rank);
  scan_part_kernel<<<NB, 1024, 0, stream>>>(deg, off, bsum);
  scan_fix_kernel<<<NB, 1024, 0, stream>>>(bsum, off,
                                           (unsigned*)(H1 + (size_t)NV * HD));
  perm_kernel<<<(EV + 255) / 256, 256, 0, stream>>>(src, dst, rank, off, gsrc);

  // layer 0: H0 -> H1 ; layer 1: H1 -> H0  (ping-pong)
  aggcomb_kernel<<<1024, 256, 0, stream>>>(
      H0, H1, gsrc, off, conv_w, conv_b,
      bn_gamma, bn_beta, bn_mean, bn_var);
  aggcomb_kernel<<<1024, 256, 0, stream>>>(
      H1, H0, gsrc, off, conv_w + 2 * HD * HD, conv_b + HD,
      bn_gamma + HD, bn_beta + HD, bn_mean + HD, bn_var + HD);

  score_kernel<<<(EV / 2 * 8 + 255) / 256, 256, 0, stream>>>(
      H0, src, dst, neg_dst, w_rel, out);
}

// Round 17
// 290.311 us; speedup vs baseline: 1.0211x; 1.0086x over previous
//
#include <hip/hip_runtime.h>
#include <hip/hip_fp16.h>

#define NV 50000
#define EV 800000
#define INF 128
#define HD 64
#define KNEG 5
#define NB ((NV + 1023) / 1024)   // 49 scan blocks

#if defined(__has_builtin)
#if __has_builtin(__builtin_amdgcn_fdot2)
#define HAS_FDOT2 1
#endif
#endif

typedef _Float16 half2r __attribute__((ext_vector_type(2)));
typedef _Float16 half8 __attribute__((ext_vector_type(8)));
typedef float f32x4 __attribute__((ext_vector_type(4)));

// dot2: c += a.lo*b.lo + a.hi*b.hi  (f16 pairs, f32 accumulate)
__device__ __forceinline__ float dot2acc(unsigned a, unsigned b, float c) {
#ifdef HAS_FDOT2
  return __builtin_amdgcn_fdot2(__builtin_bit_cast(half2r, a),
                                __builtin_bit_cast(half2r, b), c, false);
#else
  const __half2 ha = *(const __half2*)&a;
  const __half2 hb = *(const __half2*)&b;
  return c + __low2float(ha) * __low2float(hb)
           + __high2float(ha) * __high2float(hb);
#endif
}

__device__ __forceinline__ unsigned packh2(float lo, float hi) {
  return __builtin_bit_cast(unsigned, __floats2half2_rn(lo, hi));
}

// pinned 16B global load (kept from r16 score)
__device__ __forceinline__ uint4 gload16(const uint4* p) {
  uint4 r;
  asm volatile("global_load_dwordx4 %0, %1, off" : "=v"(r) : "v"(p));
  return r;
}

// ------- embed + hist fused, v7: MFMA GEMM (no LDS) -------------------
// h = feat @ W + b via mfma_f32_16x16x32_f16. Per wave-tile: 16 nodes,
// A-fragments loaded directly from global (coalesced float4, no LDS
// broadcast — the old dot2 loop made every lane read every byte of the
// tile: ~820 MB LDS traffic = the hidden DS-pipe floor). B (W) and bias
// preloaded per wave. Layouts: A lane=(row=l&15, k=8*(l>>4)+j);
// B lane=(k=8*(l>>4)+j, col=l&15); D lane=(row=4*(l>>4)+j, col=l&15)
// [m89-verified]. Bias folded into acc init (per-column).
__global__ __launch_bounds__(256) void embed_hist_kernel(
    const float* __restrict__ feat, const float* __restrict__ W,
    const float* __restrict__ b, __half* __restrict__ h,
    const int* __restrict__ dst, int* __restrict__ deg,
    unsigned short* __restrict__ rank) {
  const int lane = threadIdx.x & 63;
  const int wave = threadIdx.x >> 6;
  // zero row NV of h (gather's out-of-degree target) — folded memset
  if (blockIdx.x == 0 && threadIdx.x < 32)
    ((unsigned*)(h + (size_t)NV * HD))[threadIdx.x] = 0u;
  const int r16 = lane & 15;      // A-row / B-col / D-col
  const int kg = lane >> 4;       // k-subgroup 0..3
  // B fragments: fb[c][t][j] = W[32c + 8kg + j][16t + r16]
  half8 fb[4][4];
#pragma unroll
  for (int c = 0; c < 4; c++)
#pragma unroll
    for (int t = 0; t < 4; t++)
#pragma unroll
      for (int j = 0; j < 8; j++)
        fb[c][t][j] = (_Float16)W[(32 * c + 8 * kg + j) * HD + 16 * t + r16];
  float bias[4];
#pragma unroll
  for (int t = 0; t < 4; t++) bias[t] = b[16 * t + r16];

  const int nw = gridDim.x * 4;
  const int ntiles = NV / 16;     // 3125 exactly
  for (int tile = blockIdx.x * 4 + wave; tile < ntiles; tile += nw) {
    const int n0 = tile * 16;
    // A fragments: fa[c][j] = feat[n0 + r16][32c + 8kg + j]  (fp32->fp16)
    half8 fa[4];
#pragma unroll
    for (int c = 0; c < 4; c++) {
      const float4* fp =
          (const float4*)(feat + (size_t)(n0 + r16) * INF + 32 * c + 8 * kg);
      const float4 x0 = fp[0];
      const float4 x1 = fp[1];
      fa[c][0] = (_Float16)x0.x; fa[c][1] = (_Float16)x0.y;
      fa[c][2] = (_Float16)x0.z; fa[c][3] = (_Float16)x0.w;
      fa[c][4] = (_Float16)x1.x; fa[c][5] = (_Float16)x1.y;
      fa[c][6] = (_Float16)x1.z; fa[c][7] = (_Float16)x1.w;
    }
    f32x4 acc[4];
#pragma unroll
    for (int t = 0; t < 4; t++)
      acc[t] = (f32x4){bias[t], bias[t], bias[t], bias[t]};
#pragma unroll
    for (int c = 0; c < 4; c++) {
      acc[0] = __builtin_amdgcn_mfma_f32_16x16x32_f16(fa[c], fb[c][0],
                                                      acc[0], 0, 0, 0);
      acc[1] = __builtin_amdgcn_mfma_f32_16x16x32_f16(fa[c], fb[c][1],
                                                      acc[1], 0, 0, 0);
      acc[2] = __builtin_amdgcn_mfma_f32_16x16x32_f16(fa[c], fb[c][2],
                                                      acc[2], 0, 0, 0);
      acc[3] = __builtin_amdgcn_mfma_f32_16x16x32_f16(fa[c], fb[c][3],
                                                      acc[3], 0, 0, 0);
    }
    // D: lane holds D[4kg + j][16t + r16]
#pragma unroll
    for (int t = 0; t < 4; t++)
#pragma unroll
      for (int j = 0; j < 4; j++)
        h[(size_t)(n0 + 4 * kg + j) * HD + 16 * t + r16] =
            __float2half_rn(acc[t][j]);
  }
  // hist tail: overlaps with GEMM-bound waves of other blocks
  for (int e = blockIdx.x * 256 + threadIdx.x; e < EV; e += gridDim.x * 256) {
    const int r = atomicAdd(&deg[dst[e]], 1);
    rank[e] = (unsigned short)r;             // coalesced u16 store
  }
}

// ------- parallel scan, pass 1 ----------------------------------------
__global__ __launch_bounds__(1024) void scan_part_kernel(
    const int* __restrict__ deg, int* __restrict__ off,
    int* __restrict__ bsum) {
  __shared__ int wsum[16];
  const int tid = threadIdx.x;
  const int lane = tid & 63;
  const int w = tid >> 6;
  const int i = blockIdx.x * 1024 + tid;
  const int v = (i < NV) ? deg[i] : 0;
  int s = v;
#pragma unroll
  for (int ofs = 1; ofs < 64; ofs <<= 1) {
    int x = __shfl_up(s, ofs, 64);
    if (lane >= ofs) s += x;
  }
  if (lane == 63) wsum[w] = s;
  __syncthreads();
  if (w == 0) {
    int t2 = (lane < 16) ? wsum[lane] : 0;
#pragma unroll
    for (int ofs = 1; ofs < 16; ofs <<= 1) {
      int x = __shfl_up(t2, ofs, 64);
      if (lane >= ofs) t2 += x;
    }
    if (lane < 16) wsum[lane] = t2;
  }
  __syncthreads();
  const int base = (w > 0) ? wsum[w - 1] : 0;
  if (i < NV) off[i] = base + s - v;
  if (tid == 0) bsum[blockIdx.x] = wsum[15];
}

// ------- parallel scan, pass 2 (+ H1 zero-row init) -------------------
__global__ __launch_bounds__(1024) void scan_fix_kernel(
    const int* __restrict__ bsum, int* __restrict__ off,
    unsigned* __restrict__ h1zrow) {
  __shared__ int sbase, stot;
  const int tid = threadIdx.x;
  const int b = blockIdx.x;
  if (b == 0 && tid < 32) h1zrow[tid] = 0u;   // folded memset (128 B)
  if (tid == 0) {
    int acc = 0, tot = 0;
    for (int j = 0; j < NB; j++) {
      const int x = bsum[j];
      if (j < b) acc += x;
      tot += x;
    }
    sbase = acc;
    stot = tot;
  }
  __syncthreads();
  const int i = b * 1024 + tid;
  if (i < NV) off[i] += sbase;
  if (b == NB - 1 && tid == 0) off[NV] = stot;
}

// ------- CSR perm: no atomics, u16 payload, plain store ---------------
__global__ __launch_bounds__(256) void perm_kernel(
    const int* __restrict__ src, const int* __restrict__ dst,
    const unsigned short* __restrict__ rank, const int* __restrict__ off,
    unsigned short* __restrict__ gsrc) {
  const int e = blockIdx.x * 256 + threadIdx.x;
  if (e < EV) {
    const int pos = off[dst[e]] + (int)rank[e];
    gsrc[pos] = (unsigned short)src[e];
  }
}

// ------- fused aggregate + combine, v9 (unchanged from r13) -----------
__global__ __launch_bounds__(256) void aggcomb_kernel(
    const __half* __restrict__ hin, __half* __restrict__ hout,
    const unsigned short* __restrict__ gsrc, const int* __restrict__ off,
    const float* __restrict__ wconv, const float* __restrict__ cb,
    const float* __restrict__ gamma, const float* __restrict__ beta,
    const float* __restrict__ mean, const float* __restrict__ var) {
  __shared__ unsigned sS1[4][4][32];   // wave x slot x 64 halves (2 KB)
  __shared__ unsigned sH[4][4][32];    // wave x slot x 64 halves (2 KB)
  const int wave = threadIdx.x >> 6;
  const int lane = threadIdx.x & 63;
  const int sub = lane >> 4;   // node slot 0..3
  const int q = lane & 15;
  const int r8 = q & 7;        // uint4 slot within row (8 features)
  const int par = q >> 3;      // edge parity
  const int f = lane;          // output feature in combine phase
  unsigned Ws2[32], Wd2[32];
#pragma unroll
  for (int j = 0; j < 32; j++) {
    Ws2[j] = packh2(wconv[(2 * j) * HD + f], wconv[(2 * j + 1) * HD + f]);
    Wd2[j] = packh2(wconv[(HD + 2 * j) * HD + f],
                    wconv[(HD + 2 * j + 1) * HD + f]);
  }
  const float cbf = cb[f];
  const float gf = gamma[f];
  const float btf = beta[f];
  const float mf = mean[f];
  const float inv = rsqrtf(var[f] + 1e-3f);
  const uint4* hp = (const uint4*)hin;   // 8 uint4 per 64-half row
  const int wid = blockIdx.x * 4 + wave;
  const int nw = gridDim.x * 4;
  const int ngroups = NV / 4;            // 12500 exactly
  for (int g = wid; g < ngroups; g += nw) {
    const int n0 = g * 4;
    const int n = n0 + sub;              // this slot's node
    const int j0 = off[n];
    const int deg = off[n + 1] - j0;
    int dm = deg;                        // wave-max degree
    dm = max(dm, __shfl_xor(dm, 16, 64));
    dm = max(dm, __shfl_xor(dm, 32, 64));
    const uint4 hrv = hp[(size_t)n * 8 + r8];     // own row (par dup ok)
    float a0 = 0.f, a1 = 0.f, a2 = 0.f, a3 = 0.f;
    float a4 = 0.f, a5 = 0.f, a6 = 0.f, a7 = 0.f;
    for (int base = 0; base < dm; base += 16) {
      const int e = base + q;
      const int eid = (e < deg) ? (int)gsrc[j0 + e] : NV;  // NV = zero row
#pragma unroll
      for (int i = 0; i < 8; i++) {
        const int a = __shfl(eid, (sub << 4) | (2 * i + par), 64);
        const uint4 v = hp[(size_t)a * 8 + r8];
        const __half2 p0 = *(const __half2*)&v.x;
        const __half2 p1 = *(const __half2*)&v.y;
        const __half2 p2 = *(const __half2*)&v.z;
        const __half2 p3 = *(const __half2*)&v.w;
        a0 += __low2float(p0);  a1 += __high2float(p0);
        a2 += __low2float(p1);  a3 += __high2float(p1);
        a4 += __low2float(p2);  a5 += __high2float(p2);
        a6 += __low2float(p3);  a7 += __high2float(p3);
      }
    }
    // parity combine (lanes q and q^8 hold same features, disjoint edges)
    a0 += __shfl_xor(a0, 8, 64); a1 += __shfl_xor(a1, 8, 64);
    a2 += __shfl_xor(a2, 8, 64); a3 += __shfl_xor(a3, 8, 64);
    a4 += __shfl_xor(a4, 8, 64); a5 += __shfl_xor(a5, 8, 64);
    a6 += __shfl_xor(a6, 8, 64); a7 += __shfl_xor(a7, 8, 64);
    // hand-off via wave-private LDS, packed fp16 (no barrier)
    if (par == 0) {
      uint4 s1p;
      s1p.x = packh2(a0, a1); s1p.y = packh2(a2, a3);
      s1p.z = packh2(a4, a5); s1p.w = packh2(a6, a7);
      ((uint4*)sS1[wave][sub])[r8] = s1p;
      ((uint4*)sH[wave][sub])[r8] = hrv;          // already fp16
    }
#pragma unroll
    for (int m4 = 0; m4 < 4; m4++) {
      const uint4* s1p = (const uint4*)sS1[wave][m4];
      const uint4* hq = (const uint4*)sH[wave][m4];
      float b1a = 0.f, b1b = 0.f, b2a = 0.f, b2b = 0.f;
#pragma unroll
      for (int t = 0; t < 8; t++) {      // k8 blocks, uniform broadcasts
        const uint4 xs = s1p[t];
        const uint4 xh = hq[t];
        b1a = dot2acc(xs.x, Ws2[4 * t + 0], b1a);
        b1b = dot2acc(xs.y, Ws2[4 * t + 1], b1b);
        b1a = dot2acc(xs.z, Ws2[4 * t + 2], b1a);
        b1b = dot2acc(xs.w, Ws2[4 * t + 3], b1b);
        b2a = dot2acc(xh.x, Wd2[4 * t + 0], b2a);
        b2b = dot2acc(xh.y, Wd2[4 * t + 1], b2b);
        b2a = dot2acc(xh.z, Wd2[4 * t + 2], b2a);
        b2b = dot2acc(xh.w, Wd2[4 * t + 3], b2b);
      }
      const float s1w = b1a + b1b;
      const float hw = b2a + b2b;
      const float hvf =
          __half2float(((const __half*)sH[wave][m4])[f]);  // 2-way: free
      const float d = (float)__shfl(deg, m4 << 4, 64);
      const float agg = s1w + d * hw + d * cbf;
      const float sig = 1.f / (1.f + __expf(-agg));
      const float sp = fmaxf(hvf, 0.f) + log1pf(__expf(-fabsf(hvf)));
      float x = sig + sp;
      x = gf * (x - mf) * inv + btf;
      hout[(size_t)(n0 + m4) * HD + f] = __float2half_rn(fmaxf(x, 0.f));
    }
  }
}

// ------- scores v6 (unchanged from r16) -------------------------------
__global__ __launch_bounds__(256) void score_kernel(
    const __half* __restrict__ hh, const int* __restrict__ src,
    const int* __restrict__ dst, const int* __restrict__ neg_dst,
    const float* __restrict__ wrel, float* __restrict__ out) {
  const int tid = blockIdx.x * 256 + threadIdx.x;
  const int gid = tid >> 3;     // edge-pair group
  const int q = tid & 7;
  const int eA = gid * 2;
  if (eA >= EV) return;
  const int eB = eA + 1;
  const int lane = threadIdx.x & 63;
  const int base8 = lane & 56;  // first lane of this group
  const float4 w0 = ((const float4*)wrel)[2 * q];
  const float4 w1 = ((const float4*)wrel)[2 * q + 1];
  const __half2 wh0 = __floats2half2_rn(w0.x, w0.y);
  const __half2 wh1 = __floats2half2_rn(w0.z, w0.w);
  const __half2 wh2 = __floats2half2_rn(w1.x, w1.y);
  const __half2 wh3 = __floats2half2_rn(w1.z, w1.w);

  // two index loads per lane, by role (q: 0=src,1=dst,2..6=neg,7=dup)
  const int* ipA = (q == 0) ? (src + eA)
                 : (q == 1) ? (dst + eA)
                            : (neg_dst + (size_t)eA * KNEG + min(q - 2, KNEG - 1));
  const int* ipB = (q == 0) ? (src + eB)
                 : (q == 1) ? (dst + eB)
                            : (neg_dst + (size_t)eB * KNEG + min(q - 2, KNEG - 1));
  const int myA = *ipA;
  const int myB = *ipB;
  const int sA = __shfl(myA, base8 + 0, 64);
  const int dA = __shfl(myA, base8 + 1, 64);
  const int sB = __shfl(myB, base8 + 0, 64);
  const int dB = __shfl(myB, base8 + 1, 64);
  int ndA[KNEG], ndB[KNEG];
#pragma unroll
  for (int r = 0; r < KNEG; r++) {
    ndA[r] = __shfl(myA, base8 + 2 + r, 64);
    ndB[r] = __shfl(myB, base8 + 2 + r, 64);
  }

  const uint4* hp = (const uint4*)hh;
  const uint4 svA = gload16(hp + (size_t)sA * 8 + q);
  const uint4 dvA = gload16(hp + (size_t)dA * 8 + q);
  const uint4 svB = gload16(hp + (size_t)sB * 8 + q);
  const uint4 dvB = gload16(hp + (size_t)dB * 8 + q);
  uint4 nvA[KNEG], nvB[KNEG];
#pragma unroll
  for (int r = 0; r < KNEG; r++) {
    nvA[r] = gload16(hp + (size_t)ndA[r] * 8 + q);
    nvB[r] = gload16(hp + (size_t)ndB[r] * 8 + q);
  }
  asm volatile("s_waitcnt vmcnt(0)" ::: "memory");
  __builtin_amdgcn_sched_barrier(0);   // rule #18: no consumer hoisting

#define AW(sv, a0, a1, a2, a3)                                        \
  const unsigned a0 = __builtin_bit_cast(unsigned,                    \
      __hmul2(*(const __half2*)&sv.x, wh0));                          \
  const unsigned a1 = __builtin_bit_cast(unsigned,                    \
      __hmul2(*(const __half2*)&sv.y, wh1));                          \
  const unsigned a2 = __builtin_bit_cast(unsigned,                    \
      __hmul2(*(const __half2*)&sv.z, wh2));                          \
  const unsigned a3 = __builtin_bit_cast(unsigned,                    \
      __hmul2(*(const __half2*)&sv.w, wh3));
  AW(svA, aA0, aA1, aA2, aA3)
  AW(svB, aB0, aB1, aB2, aB3)
#undef AW
#define DOT(a0, a1, a2, a3, v)                                        \
  dot2acc(a3, v.w, dot2acc(a2, v.z, dot2acc(a1, v.y, dot2acc(a0, v.x, 0.f))))

  float uA0 = DOT(aA0, aA1, aA2, aA3, dvA);
  float uA1 = DOT(aA0, aA1, aA2, aA3, nvA[0]);
  float uA2 = DOT(aA0, aA1, aA2, aA3, nvA[1]);
  float uA3 = DOT(aA0, aA1, aA2, aA3, nvA[2]);
  float uA4 = DOT(aA0, aA1, aA2, aA3, nvA[3]);
  float uA5 = DOT(aA0, aA1, aA2, aA3, nvA[4]);
  float uB0 = DOT(aB0, aB1, aB2, aB3, dvB);
  float uB1 = DOT(aB0, aB1, aB2, aB3, nvB[0]);
  float uB2 = DOT(aB0, aB1, aB2, aB3, nvB[1]);
  float uB3 = DOT(aB0, aB1, aB2, aB3, nvB[2]);
  float uB4 = DOT(aB0, aB1, aB2, aB3, nvB[3]);
  float uB5 = DOT(aB0, aB1, aB2, aB3, nvB[4]);
#undef DOT

#define RSCAT(v0, v1, v2, v3, v4, v5)                                 \
  {                                                                   \
    const bool hi = (q & 4) != 0;                                     \
    float t0 = hi ? v0 : v4, t1 = hi ? v1 : v5;                       \
    float t2 = hi ? v2 : 0.f, t3 = hi ? v3 : 0.f;                     \
    t0 = __shfl_xor(t0, 4, 64); t1 = __shfl_xor(t1, 4, 64);           \
    t2 = __shfl_xor(t2, 4, 64); t3 = __shfl_xor(t3, 4, 64);           \
    v0 = (hi ? v4 : v0) + t0;                                         \
    v1 = (hi ? v5 : v1) + t1;                                         \
    v2 = (hi ? 0.f : v2) + t2;                                        \
    v3 = (hi ? 0.f : v3) + t3;                                        \
  }                                                                   \
  {                                                                   \
    const bool hi = (q & 2) != 0;                                     \
    float t0 = hi ? v0 : v2, t1 = hi ? v1 : v3;                       \
    t0 = __shfl_xor(t0, 2, 64); t1 = __shfl_xor(t1, 2, 64);           \
    v0 = (hi ? v2 : v0) + t0;                                         \
    v1 = (hi ? v3 : v1) + t1;                                         \
  }                                                                   \
  {                                                                   \
    const bool hi = (q & 1) != 0;                                     \
    float t0 = hi ? v0 : v1;                                          \
    t0 = __shfl_xor(t0, 1, 64);                                       \
    v0 = (hi ? v1 : v0) + t0;                                         \
  }
  RSCAT(uA0, uA1, uA2, uA3, uA4, uA5)
  RSCAT(uB0, uB1, uB2, uB3, uB4, uB5)
#undef RSCAT

  if (q == 0) {
    __builtin_nontemporal_store(uA0, &out[eA]);
    __builtin_nontemporal_store(uB0, &out[eB]);
  } else if (q <= KNEG) {
    __builtin_nontemporal_store(
        uA0, &out[(size_t)EV + (size_t)eA * KNEG + (q - 1)]);
    __builtin_nontemporal_store(
        uB0, &out[(size_t)EV + (size_t)eB * KNEG + (q - 1)]);
  }
}

extern "C" void kernel_launch(void* const* d_in, const int* in_sizes, int n_in,
                              void* d_out, int out_size, void* d_ws, size_t ws_size,
                              hipStream_t stream) {
  const float* node_feat = (const float*)d_in[0];
  const float* emb_w     = (const float*)d_in[1];
  const float* emb_b     = (const float*)d_in[2];
  const float* conv_w    = (const float*)d_in[3];
  const float* conv_b    = (const float*)d_in[4];
  const float* bn_gamma  = (const float*)d_in[5];
  const float* bn_beta   = (const float*)d_in[6];
  const float* bn_mean   = (const float*)d_in[7];
  const float* bn_var    = (const float*)d_in[8];
  const float* w_rel     = (const float*)d_in[9];
  const int*   src       = (const int*)d_in[10];
  const int*   dst       = (const int*)d_in[11];
  const int*   neg_dst   = (const int*)d_in[12];
  float* out = (float*)d_out;

  // ws layout: H0 | H1 (each NV+1 rows; row NV = zeros) | off | gsrc | bsum
  __half* H0 = (__half*)d_ws;                        // (NV+1) x HD fp16
  __half* H1 = H0 + (size_t)(NV + 1) * HD;
  int*   off  = (int*)(H1 + (size_t)(NV + 1) * HD);
  unsigned short* gsrc = (unsigned short*)(off + (NV + 1));
  int*   bsum = (int*)(gsrc + EV);
  int*   deg  = (int*)H1;
  unsigned short* rank = ((unsigned short*)H1) + 2 * NV;

  hipMemsetAsync(deg, 0, (size_t)NV * sizeof(int), stream);
  embed_hist_kernel<<<1024, 256, 0, stream>>>(node_feat, emb_w, emb_b, H0,
                                              dst, deg, rank);
  scan_part_kernel<<<NB, 1024, 0, stream>>>(deg, off, bsum);
  scan_fix_kernel<<<NB, 1024, 0, stream>>>(bsum, off,
                                           (unsigned*)(H1 + (size_t)NV * HD));
  perm_kernel<<<(EV + 255) / 256, 256, 0, stream>>>(src, dst, rank, off, gsrc);

  // layer 0: H0 -> H1 ; layer 1: H1 -> H0  (ping-pong)
  aggcomb_kernel<<<1024, 256, 0, stream>>>(
      H0, H1, gsrc, off, conv_w, conv_b,
      bn_gamma, bn_beta, bn_mean, bn_var);
  aggcomb_kernel<<<1024, 256, 0, stream>>>(
      H1, H0, gsrc, off, conv_w + 2 * HD * HD, conv_b + HD,
      bn_gamma + HD, bn_beta + HD, bn_mean + HD, bn_var + HD);

  score_kernel<<<(EV / 2 * 8 + 255) / 256, 256, 0, stream>>>(
      H0, src, dst, neg_dst, w_rel, out);
}